// Round 9
// baseline (130.839 us; speedup 1.0000x reference)
//
#include <hip/hip_runtime.h>
#include <hip/hip_bf16.h>

namespace {

constexpr int S = 2048;
constexpr int D = 64;
constexpr int BH = 24;        // 2 batches * 12 heads
constexpr int QT = 64;        // q rows per block
constexpr int KT = 64;        // keys per tile
constexpr int NKT = S / KT;   // 32
constexpr int KSPLIT = 4;     // k-range split for rowsum kernel
constexpr int SK = S / KSPLIT;      // 512 keys per split
constexpr int NKT2 = SK / KT;       // 8 tiles per split
constexpr int PAD = 72;       // LDS row stride in ushorts (16B-aligned rows; R2 lesson)

typedef __attribute__((ext_vector_type(8))) __bf16 bf16x8;
typedef __attribute__((ext_vector_type(4))) __bf16 bf16x4;
typedef __attribute__((ext_vector_type(4))) float  f32x4;

// f32x4 -> bf16x4 via native v_cvt_pk_bf16_f32 (RNE)
__device__ inline bf16x4 cvt4(f32x4 f) {
    return __builtin_convertvector(f, bf16x4);
}

// ========== kernel 1: partial row sums of exp(scores/64) over a 512-key range ==========
// LDS 27.6KB -> 5 blocks/CU resident (20 waves); 3072 blocks total.
__global__ __launch_bounds__(256, 5)
void rowsum_partial(const float* __restrict__ q,
                    const float* __restrict__ k,
                    float* __restrict__ psum) {
    __shared__ unsigned short Ks[2][KT][PAD];
    __shared__ unsigned short Qs[QT][PAD];

    const int tid  = threadIdx.x;
    const int wid  = tid >> 6;
    const int lane = tid & 63;
    const int g    = lane >> 4;
    const int r16  = lane & 15;
    const int bh   = blockIdx.y;
    const int q0   = blockIdx.x * QT;
    const int kz   = blockIdx.z;     // 0..3

    const float* qg = q + ((size_t)bh * S + q0) * D;
    const float* kg = k + ((size_t)bh * S + kz * SK) * D;

    #pragma unroll
    for (int ii = 0; ii < 4; ++ii) {
        int idx = tid + ii * 256;
        int r = idx >> 4, c = (idx & 15) * 4;
        f32x4 f = *reinterpret_cast<const f32x4*>(qg + r * D + c);
        *reinterpret_cast<bf16x4*>(&Qs[r][c]) = cvt4(f);
    }
    __syncthreads();
    const bf16x8 bQ0 = *(const bf16x8*)&Qs[wid * 16 + r16][g * 8];
    const bf16x8 bQ1 = *(const bf16x8*)&Qs[wid * 16 + r16][32 + g * 8];

    float rs0 = 0.f, rs1 = 0.f;
    f32x4 pK[4];

    #pragma unroll
    for (int ii = 0; ii < 4; ++ii) {
        int idx = tid + ii * 256;
        int r = idx >> 4, c = (idx & 15) * 4;
        pK[ii] = *reinterpret_cast<const f32x4*>(kg + r * D + c);
    }
    #pragma unroll
    for (int ii = 0; ii < 4; ++ii) {
        int idx = tid + ii * 256;
        int r = idx >> 4, c = (idx & 15) * 4;
        *reinterpret_cast<bf16x4*>(&Ks[0][r][c]) = cvt4(pK[ii]);
    }
    __syncthreads();

    for (int t = 0; t < NKT2; ++t) {
        const int cur = t & 1;
        if (t + 1 < NKT2) {
            const float* ktg = kg + (size_t)(t + 1) * KT * D;
            #pragma unroll
            for (int ii = 0; ii < 4; ++ii) {
                int idx = tid + ii * 256;
                int r = idx >> 4, c = (idx & 15) * 4;
                pK[ii] = *reinterpret_cast<const f32x4*>(ktg + r * D + c);
            }
        }
        #pragma unroll
        for (int cf = 0; cf < 4; ++cf) {
            bf16x8 aK0 = *(const bf16x8*)&Ks[cur][cf * 16 + r16][g * 8];
            bf16x8 aK1 = *(const bf16x8*)&Ks[cur][cf * 16 + r16][32 + g * 8];
            f32x4 acc = {0.f, 0.f, 0.f, 0.f};
            acc = __builtin_amdgcn_mfma_f32_16x16x32_bf16(aK0, bQ0, acc, 0, 0, 0);
            acc = __builtin_amdgcn_mfma_f32_16x16x32_bf16(aK1, bQ1, acc, 0, 0, 0);
            rs0 += __expf(acc[0] * (1.0f / 64.0f)) + __expf(acc[2] * (1.0f / 64.0f));
            rs1 += __expf(acc[1] * (1.0f / 64.0f)) + __expf(acc[3] * (1.0f / 64.0f));
        }
        if (t + 1 < NKT2) {
            const int nxt = (t + 1) & 1;
            #pragma unroll
            for (int ii = 0; ii < 4; ++ii) {
                int idx = tid + ii * 256;
                int r = idx >> 4, c = (idx & 15) * 4;
                *reinterpret_cast<bf16x4*>(&Ks[nxt][r][c]) = cvt4(pK[ii]);
            }
            __syncthreads();
        }
    }
    float rs = rs0 + rs1;
    rs += __shfl_xor(rs, 16, 64);
    rs += __shfl_xor(rs, 32, 64);
    if (lane < 16)
        psum[((size_t)kz * BH + bh) * S + q0 + wid * 16 + lane] = rs;
}

// ========== kernel 2: R8 phase-2 — scores, attn (full-line nt), PV ==========
__global__ __launch_bounds__(256, 3)
void attn_pv(const float* __restrict__ q,
             const float* __restrict__ k,
             const float* __restrict__ v,
             const float* __restrict__ psum,
             float* __restrict__ out,
             float* __restrict__ attn) {
    __shared__ unsigned short Ks[2][KT][PAD];
    __shared__ unsigned short Vt[2][D][PAD];   // Vt[d][key]
    __shared__ unsigned short QPs[QT][PAD];    // Q staging, then P (rows wave-private)

    const int tid  = threadIdx.x;
    const int wid  = tid >> 6;
    const int lane = tid & 63;
    const int g    = lane >> 4;
    const int r16  = lane & 15;
    const int sr   = lane >> 3;      // store mapping: 8 rows x 8 lanes
    const int sc   = (lane & 7) * 4; // 4 contiguous elems; 8 lanes = 128B/row
    const int bh   = blockIdx.y;
    const int q0   = blockIdx.x * QT;

    const float* qg = q + ((size_t)bh * S + q0) * D;
    const float* kg = k + (size_t)bh * S * D;
    const float* vg = v + (size_t)bh * S * D;
    float* attng = attn + ((size_t)bh * S + q0) * S;
    float* outg  = out  + ((size_t)bh * S + q0) * D;

    // ---- stage Q tile fp32 -> bf16 ----
    #pragma unroll
    for (int ii = 0; ii < 4; ++ii) {
        int idx = tid + ii * 256;
        int r = idx >> 4, c = (idx & 15) * 4;
        f32x4 f = *reinterpret_cast<const f32x4*>(qg + r * D + c);
        *reinterpret_cast<bf16x4*>(&QPs[r][c]) = cvt4(f);
    }
    __syncthreads();
    const bf16x8 bQ0 = *(const bf16x8*)&QPs[wid * 16 + r16][g * 8];
    const bf16x8 bQ1 = *(const bf16x8*)&QPs[wid * 16 + r16][32 + g * 8];

    // ---- gather partial row sums (fixed order -> deterministic) ----
    const size_t rowi = (size_t)bh * S + q0 + wid * 16 + r16;
    const float p0 = psum[rowi];
    const float p1 = psum[(size_t)BH * S + rowi];
    const float p2 = psum[(size_t)2 * BH * S + rowi];
    const float p3 = psum[(size_t)3 * BH * S + rowi];
    const float inv = 1.0f / (((p0 + p1) + p2) + p3);

    f32x4 oacc[4];
    #pragma unroll
    for (int n = 0; n < 4; ++n) oacc[n] = {0.f, 0.f, 0.f, 0.f};

    f32x4 pK[4], pV[4];
    const int vk0 = (tid & 15) * 4;   // V: 4 rows x float4 -> transposed b64 writes
    const int vc  = (tid >> 4) * 4;

    #pragma unroll
    for (int ii = 0; ii < 4; ++ii) {
        int idx = tid + ii * 256;
        int r = idx >> 4, c = (idx & 15) * 4;
        pK[ii] = *reinterpret_cast<const f32x4*>(kg + r * D + c);
        pV[ii] = *reinterpret_cast<const f32x4*>(vg + (vk0 + ii) * D + vc);
    }
    #pragma unroll
    for (int ii = 0; ii < 4; ++ii) {
        int idx = tid + ii * 256;
        int r = idx >> 4, c = (idx & 15) * 4;
        *reinterpret_cast<bf16x4*>(&Ks[0][r][c]) = cvt4(pK[ii]);
    }
    #pragma unroll
    for (int j = 0; j < 4; ++j) {
        f32x4 col = { pV[0][j], pV[1][j], pV[2][j], pV[3][j] };
        *reinterpret_cast<bf16x4*>(&Vt[0][vc + j][vk0]) = cvt4(col);
    }
    __syncthreads();

    for (int t = 0; t < NKT; ++t) {
        const int cur = t & 1;
        if (t + 1 < NKT) {
            const float* ktg = kg + (size_t)(t + 1) * KT * D;
            const float* vtg = vg + (size_t)(t + 1) * KT * D;
            #pragma unroll
            for (int ii = 0; ii < 4; ++ii) {
                int idx = tid + ii * 256;
                int r = idx >> 4, c = (idx & 15) * 4;
                pK[ii] = *reinterpret_cast<const f32x4*>(ktg + r * D + c);
                pV[ii] = *reinterpret_cast<const f32x4*>(vtg + (vk0 + ii) * D + vc);
            }
        }
        // QK^T (swapped); P (normalized, bf16) -> own-wave LDS rows
        #pragma unroll
        for (int cf = 0; cf < 4; ++cf) {
            bf16x8 aK0 = *(const bf16x8*)&Ks[cur][cf * 16 + r16][g * 8];
            bf16x8 aK1 = *(const bf16x8*)&Ks[cur][cf * 16 + r16][32 + g * 8];
            f32x4 acc = {0.f, 0.f, 0.f, 0.f};
            acc = __builtin_amdgcn_mfma_f32_16x16x32_bf16(aK0, bQ0, acc, 0, 0, 0);
            acc = __builtin_amdgcn_mfma_f32_16x16x32_bf16(aK1, bQ1, acc, 0, 0, 0);
            f32x4 pst;
            #pragma unroll
            for (int e = 0; e < 4; ++e)
                pst[e] = __expf(acc[e] * (1.0f / 64.0f)) * inv;
            *reinterpret_cast<bf16x4*>(&QPs[wid * 16 + r16][cf * 16 + g * 4]) = cvt4(pst);
        }
        // PV: A = P (own-wave rows just written; same-wave DS ordering)
        bf16x8 aP0 = *(const bf16x8*)&QPs[wid * 16 + r16][g * 8];
        bf16x8 aP1 = *(const bf16x8*)&QPs[wid * 16 + r16][32 + g * 8];
        #pragma unroll
        for (int n = 0; n < 4; ++n) {
            bf16x8 bv0 = *(const bf16x8*)&Vt[cur][n * 16 + r16][g * 8];
            bf16x8 bv1 = *(const bf16x8*)&Vt[cur][n * 16 + r16][32 + g * 8];
            oacc[n] = __builtin_amdgcn_mfma_f32_16x16x32_bf16(aP0, bv0, oacc[n], 0, 0, 0);
            oacc[n] = __builtin_amdgcn_mfma_f32_16x16x32_bf16(aP1, bv1, oacc[n], 0, 0, 0);
        }
        // attn store from QPs (bf16->f32): 8 rows x (8 lanes x 16B) = full 128B lines
        #pragma unroll
        for (int h = 0; h < 2; ++h) {
            const int row = wid * 16 + h * 8 + sr;
            #pragma unroll
            for (int half = 0; half < 2; ++half) {
                bf16x4 pb = *reinterpret_cast<const bf16x4*>(&QPs[row][half * 32 + sc]);
                f32x4 pf = __builtin_convertvector(pb, f32x4);
                __builtin_nontemporal_store(pf, reinterpret_cast<f32x4*>(
                    attng + (size_t)row * S + t * KT + half * 32 + sc));
            }
        }
        if (t + 1 < NKT) {
            const int nxt = (t + 1) & 1;
            #pragma unroll
            for (int ii = 0; ii < 4; ++ii) {
                int idx = tid + ii * 256;
                int r = idx >> 4, c = (idx & 15) * 4;
                *reinterpret_cast<bf16x4*>(&Ks[nxt][r][c]) = cvt4(pK[ii]);
            }
            #pragma unroll
            for (int j = 0; j < 4; ++j) {
                f32x4 col = { pV[0][j], pV[1][j], pV[2][j], pV[3][j] };
                *reinterpret_cast<bf16x4*>(&Vt[nxt][vc + j][vk0]) = cvt4(col);
            }
            __syncthreads();
        }
    }

    // ---- epilogue: out tile via LDS bounce (Ks dead) -> full-line stores ----
    __syncthreads();
    float* KsF = reinterpret_cast<float*>(&Ks[0][0][0]);   // 64 x 72 f32
    #pragma unroll
    for (int n = 0; n < 4; ++n) {
        #pragma unroll
        for (int e = 0; e < 4; ++e) {
            KsF[(wid * 16 + g * 4 + e) * 72 + n * 16 + r16] = oacc[n][e];
        }
    }
    __syncthreads();
    #pragma unroll
    for (int h = 0; h < 2; ++h) {
        const int row = wid * 16 + h * 8 + sr;
        #pragma unroll
        for (int half = 0; half < 2; ++half) {
            f32x4 o = *reinterpret_cast<const f32x4*>(&KsF[row * 72 + half * 32 + sc]);
            __builtin_nontemporal_store(o, reinterpret_cast<f32x4*>(
                outg + (size_t)row * D + half * 32 + sc));
        }
    }
}

// ---------------- fallback (proven R8 monolith) if ws too small ----------------
__global__ __launch_bounds__(256, 3)
void sdpa_fallback(const float* __restrict__ q,
                   const float* __restrict__ k,
                   const float* __restrict__ v,
                   float* __restrict__ out,
                   float* __restrict__ attn) {
    __shared__ unsigned short Ks[2][KT][PAD];
    __shared__ unsigned short Vt[2][D][PAD];
    __shared__ unsigned short QPs[QT][PAD];

    const int tid  = threadIdx.x;
    const int wid  = tid >> 6;
    const int lane = tid & 63;
    const int g    = lane >> 4;
    const int r16  = lane & 15;
    const int sr   = lane >> 3;
    const int sc   = (lane & 7) * 4;
    const int bh   = blockIdx.y;
    const int q0   = blockIdx.x * QT;

    const float* qg = q + ((size_t)bh * S + q0) * D;
    const float* kg = k + (size_t)bh * S * D;
    const float* vg = v + (size_t)bh * S * D;
    float* attng = attn + ((size_t)bh * S + q0) * S;
    float* outg  = out  + ((size_t)bh * S + q0) * D;

    #pragma unroll
    for (int ii = 0; ii < 4; ++ii) {
        int idx = tid + ii * 256;
        int r = idx >> 4, c = (idx & 15) * 4;
        f32x4 f = *reinterpret_cast<const f32x4*>(qg + r * D + c);
        *reinterpret_cast<bf16x4*>(&QPs[r][c]) = cvt4(f);
    }
    __syncthreads();
    const bf16x8 bQ0 = *(const bf16x8*)&QPs[wid * 16 + r16][g * 8];
    const bf16x8 bQ1 = *(const bf16x8*)&QPs[wid * 16 + r16][32 + g * 8];

    float rs = 0.0f;
    f32x4 pK[4];

    #pragma unroll
    for (int ii = 0; ii < 4; ++ii) {
        int idx = tid + ii * 256;
        int r = idx >> 4, c = (idx & 15) * 4;
        pK[ii] = *reinterpret_cast<const f32x4*>(kg + r * D + c);
    }
    #pragma unroll
    for (int ii = 0; ii < 4; ++ii) {
        int idx = tid + ii * 256;
        int r = idx >> 4, c = (idx & 15) * 4;
        *reinterpret_cast<bf16x4*>(&Ks[0][r][c]) = cvt4(pK[ii]);
    }
    __syncthreads();

    for (int t = 0; t < NKT; ++t) {
        const int cur = t & 1;
        if (t + 1 < NKT) {
            const float* ktg = kg + (size_t)(t + 1) * KT * D;
            #pragma unroll
            for (int ii = 0; ii < 4; ++ii) {
                int idx = tid + ii * 256;
                int r = idx >> 4, c = (idx & 15) * 4;
                pK[ii] = *reinterpret_cast<const f32x4*>(ktg + r * D + c);
            }
        }
        #pragma unroll
        for (int cf = 0; cf < 4; ++cf) {
            bf16x8 aK0 = *(const bf16x8*)&Ks[cur][cf * 16 + r16][g * 8];
            bf16x8 aK1 = *(const bf16x8*)&Ks[cur][cf * 16 + r16][32 + g * 8];
            f32x4 acc = {0.f, 0.f, 0.f, 0.f};
            acc = __builtin_amdgcn_mfma_f32_16x16x32_bf16(aK0, bQ0, acc, 0, 0, 0);
            acc = __builtin_amdgcn_mfma_f32_16x16x32_bf16(aK1, bQ1, acc, 0, 0, 0);
            #pragma unroll
            for (int e = 0; e < 4; ++e)
                rs += __expf(acc[e] * (1.0f / 64.0f));
        }
        if (t + 1 < NKT) {
            const int nxt = (t + 1) & 1;
            #pragma unroll
            for (int ii = 0; ii < 4; ++ii) {
                int idx = tid + ii * 256;
                int r = idx >> 4, c = (idx & 15) * 4;
                *reinterpret_cast<bf16x4*>(&Ks[nxt][r][c]) = cvt4(pK[ii]);
            }
            __syncthreads();
        }
    }
    rs += __shfl_xor(rs, 16, 64);
    rs += __shfl_xor(rs, 32, 64);
    const float inv = 1.0f / rs;

    f32x4 oacc[4];
    #pragma unroll
    for (int n = 0; n < 4; ++n) oacc[n] = {0.f, 0.f, 0.f, 0.f};

    f32x4 pV[4];
    const int vk0 = (tid & 15) * 4;
    const int vc  = (tid >> 4) * 4;

    #pragma unroll
    for (int ii = 0; ii < 4; ++ii) {
        int idx = tid + ii * 256;
        int r = idx >> 4, c = (idx & 15) * 4;
        pK[ii] = *reinterpret_cast<const f32x4*>(kg + r * D + c);
        pV[ii] = *reinterpret_cast<const f32x4*>(vg + (vk0 + ii) * D + vc);
    }
    #pragma unroll
    for (int ii = 0; ii < 4; ++ii) {
        int idx = tid + ii * 256;
        int r = idx >> 4, c = (idx & 15) * 4;
        *reinterpret_cast<bf16x4*>(&Ks[0][r][c]) = cvt4(pK[ii]);
    }
    #pragma unroll
    for (int j = 0; j < 4; ++j) {
        f32x4 col = { pV[0][j], pV[1][j], pV[2][j], pV[3][j] };
        *reinterpret_cast<bf16x4*>(&Vt[0][vc + j][vk0]) = cvt4(col);
    }
    __syncthreads();

    for (int t = 0; t < NKT; ++t) {
        const int cur = t & 1;
        if (t + 1 < NKT) {
            const float* ktg = kg + (size_t)(t + 1) * KT * D;
            const float* vtg = vg + (size_t)(t + 1) * KT * D;
            #pragma unroll
            for (int ii = 0; ii < 4; ++ii) {
                int idx = tid + ii * 256;
                int r = idx >> 4, c = (idx & 15) * 4;
                pK[ii] = *reinterpret_cast<const f32x4*>(ktg + r * D + c);
                pV[ii] = *reinterpret_cast<const f32x4*>(vtg + (vk0 + ii) * D + vc);
            }
        }
        #pragma unroll
        for (int cf = 0; cf < 4; ++cf) {
            bf16x8 aK0 = *(const bf16x8*)&Ks[cur][cf * 16 + r16][g * 8];
            bf16x8 aK1 = *(const bf16x8*)&Ks[cur][cf * 16 + r16][32 + g * 8];
            f32x4 acc = {0.f, 0.f, 0.f, 0.f};
            acc = __builtin_amdgcn_mfma_f32_16x16x32_bf16(aK0, bQ0, acc, 0, 0, 0);
            acc = __builtin_amdgcn_mfma_f32_16x16x32_bf16(aK1, bQ1, acc, 0, 0, 0);
            f32x4 pst;
            #pragma unroll
            for (int e = 0; e < 4; ++e)
                pst[e] = __expf(acc[e] * (1.0f / 64.0f)) * inv;
            *reinterpret_cast<bf16x4*>(&QPs[wid * 16 + r16][cf * 16 + g * 4]) = cvt4(pst);
        }
        bf16x8 aP0 = *(const bf16x8*)&QPs[wid * 16 + r16][g * 8];
        bf16x8 aP1 = *(const bf16x8*)&QPs[wid * 16 + r16][32 + g * 8];
        #pragma unroll
        for (int n = 0; n < 4; ++n) {
            bf16x8 bv0 = *(const bf16x8*)&Vt[cur][n * 16 + r16][g * 8];
            bf16x8 bv1 = *(const bf16x8*)&Vt[cur][n * 16 + r16][32 + g * 8];
            oacc[n] = __builtin_amdgcn_mfma_f32_16x16x32_bf16(aP0, bv0, oacc[n], 0, 0, 0);
            oacc[n] = __builtin_amdgcn_mfma_f32_16x16x32_bf16(aP1, bv1, oacc[n], 0, 0, 0);
        }
        #pragma unroll
        for (int h = 0; h < 2; ++h) {
            const int row = wid * 16 + h * 8 + sr;
            #pragma unroll
            for (int half = 0; half < 2; ++half) {
                bf16x4 pb = *reinterpret_cast<const bf16x4*>(&QPs[row][half * 32 + sc]);
                f32x4 pf = __builtin_convertvector(pb, f32x4);
                __builtin_nontemporal_store(pf, reinterpret_cast<f32x4*>(
                    attng + (size_t)row * S + t * KT + half * 32 + sc));
            }
        }
        if (t + 1 < NKT) {
            const int nxt = (t + 1) & 1;
            #pragma unroll
            for (int ii = 0; ii < 4; ++ii) {
                int idx = tid + ii * 256;
                int r = idx >> 4, c = (idx & 15) * 4;
                *reinterpret_cast<bf16x4*>(&Ks[nxt][r][c]) = cvt4(pK[ii]);
            }
            #pragma unroll
            for (int j = 0; j < 4; ++j) {
                f32x4 col = { pV[0][j], pV[1][j], pV[2][j], pV[3][j] };
                *reinterpret_cast<bf16x4*>(&Vt[nxt][vc + j][vk0]) = cvt4(col);
            }
            __syncthreads();
        }
    }

    __syncthreads();
    float* KsF = reinterpret_cast<float*>(&Ks[0][0][0]);
    #pragma unroll
    for (int n = 0; n < 4; ++n) {
        #pragma unroll
        for (int e = 0; e < 4; ++e) {
            KsF[(wid * 16 + g * 4 + e) * 72 + n * 16 + r16] = oacc[n][e];
        }
    }
    __syncthreads();
    #pragma unroll
    for (int h = 0; h < 2; ++h) {
        const int row = wid * 16 + h * 8 + sr;
        #pragma unroll
        for (int half = 0; half < 2; ++half) {
            f32x4 o = *reinterpret_cast<const f32x4*>(&KsF[row * 72 + half * 32 + sc]);
            __builtin_nontemporal_store(o, reinterpret_cast<f32x4*>(
                outg + (size_t)row * D + half * 32 + sc));
        }
    }
}

} // namespace

extern "C" void kernel_launch(void* const* d_in, const int* in_sizes, int n_in,
                              void* d_out, int out_size, void* d_ws, size_t ws_size,
                              hipStream_t stream) {
    const float* q = (const float*)d_in[0];
    const float* k = (const float*)d_in[1];
    const float* v = (const float*)d_in[2];
    float* out  = (float*)d_out;
    float* attn = out + (size_t)BH * S * D;   // outputs concatenated: (out, attn)

    constexpr size_t PS_BYTES = (size_t)KSPLIT * BH * S * sizeof(float);   // 786 KB

    if (ws_size >= PS_BYTES) {
        float* psum = (float*)d_ws;
        rowsum_partial<<<dim3(S / QT, BH, KSPLIT), 256, 0, stream>>>(q, k, psum);
        attn_pv<<<dim3(S / QT, BH), 256, 0, stream>>>(q, k, v, psum, out, attn);
    } else {
        sdpa_fallback<<<dim3(S / QT, BH), 256, 0, stream>>>(q, k, v, out, attn);
    }
}

// Round 10
// 129.463 us; speedup vs baseline: 1.0106x; 1.0106x over previous
//
#include <hip/hip_runtime.h>
#include <hip/hip_bf16.h>

namespace {

constexpr int S = 2048;
constexpr int D = 64;
constexpr int BH = 24;        // 2 batches * 12 heads
constexpr int QT = 64;        // q rows per block
constexpr int KT = 64;        // keys per tile
constexpr int NKT = S / KT;   // 32
constexpr int PAD = 72;       // LDS row stride in ushorts (16B-aligned rows; R2 lesson)

typedef __attribute__((ext_vector_type(8))) __bf16 bf16x8;
typedef __attribute__((ext_vector_type(4))) __bf16 bf16x4;
typedef __attribute__((ext_vector_type(4))) float  f32x4;

// f32x4 -> bf16x4 via native v_cvt_pk_bf16_f32 (RNE)
__device__ inline bf16x4 cvt4(f32x4 f) {
    return __builtin_convertvector(f, bf16x4);
}

__global__ __launch_bounds__(256, 3)
void sdpa_kernel(const float* __restrict__ q,
                 const float* __restrict__ k,
                 const float* __restrict__ v,
                 float* __restrict__ out,
                 float* __restrict__ attn) {
    __shared__ unsigned short Ks[2][KT][PAD];
    __shared__ unsigned short Vt[2][D][PAD];   // Vt[d][key]
    __shared__ unsigned short QPs[QT][PAD];    // Q staging, then P (rows wave-private)

    const int tid  = threadIdx.x;
    const int wid  = tid >> 6;       // wave 0..3 owns q rows [wid*16, wid*16+16)
    const int lane = tid & 63;
    const int g    = lane >> 4;      // 16-lane group
    const int r16  = lane & 15;      // q row within wave strip (swapped layout)
    const int sr   = lane >> 3;      // store mapping: 8 rows x 8 lanes
    const int sc   = (lane & 7) * 4; // 4 contiguous elems; 8 lanes = 128B/row
    const int bh   = blockIdx.y;
    const int q0   = blockIdx.x * QT;

    const float* qg = q + ((size_t)bh * S + q0) * D;
    const float* kg = k + (size_t)bh * S * D;
    const float* vg = v + (size_t)bh * S * D;
    float* attng = attn + ((size_t)bh * S + q0) * S;
    float* outg  = out  + ((size_t)bh * S + q0) * D;

    // ---- stage Q tile (QT x D) fp32 -> bf16 LDS ----
    #pragma unroll
    for (int ii = 0; ii < 4; ++ii) {
        int idx = tid + ii * 256;
        int r = idx >> 4, c = (idx & 15) * 4;
        f32x4 f = *reinterpret_cast<const f32x4*>(qg + r * D + c);
        *reinterpret_cast<bf16x4*>(&QPs[r][c]) = cvt4(f);
    }
    __syncthreads();
    // B-frag (swapped): lane holds Q[q = r16][d = g*8 + j]
    const bf16x8 bQ0 = *(const bf16x8*)&QPs[wid * 16 + r16][g * 8];
    const bf16x8 bQ1 = *(const bf16x8*)&QPs[wid * 16 + r16][32 + g * 8];

    // ================= phase 1: row sums of exp(scores/64) =================
    float rs = 0.0f;
    f32x4 pK[4];

    #pragma unroll
    for (int ii = 0; ii < 4; ++ii) {
        int idx = tid + ii * 256;
        int r = idx >> 4, c = (idx & 15) * 4;
        pK[ii] = *reinterpret_cast<const f32x4*>(kg + r * D + c);
    }
    #pragma unroll
    for (int ii = 0; ii < 4; ++ii) {
        int idx = tid + ii * 256;
        int r = idx >> 4, c = (idx & 15) * 4;
        *reinterpret_cast<bf16x4*>(&Ks[0][r][c]) = cvt4(pK[ii]);
    }
    __syncthreads();

    for (int t = 0; t < NKT; ++t) {
        const int cur = t & 1;
        if (t + 1 < NKT) {   // prefetch next tile; latency hides under compute
            const float* ktg = kg + (size_t)(t + 1) * KT * D;
            #pragma unroll
            for (int ii = 0; ii < 4; ++ii) {
                int idx = tid + ii * 256;
                int r = idx >> 4, c = (idx & 15) * 4;
                pK[ii] = *reinterpret_cast<const f32x4*>(ktg + r * D + c);
            }
        }
        #pragma unroll
        for (int cf = 0; cf < 4; ++cf) {
            bf16x8 aK0 = *(const bf16x8*)&Ks[cur][cf * 16 + r16][g * 8];
            bf16x8 aK1 = *(const bf16x8*)&Ks[cur][cf * 16 + r16][32 + g * 8];
            f32x4 acc = {0.f, 0.f, 0.f, 0.f};
            acc = __builtin_amdgcn_mfma_f32_16x16x32_bf16(aK0, bQ0, acc, 0, 0, 0);
            acc = __builtin_amdgcn_mfma_f32_16x16x32_bf16(aK1, bQ1, acc, 0, 0, 0);
            #pragma unroll
            for (int e = 0; e < 4; ++e)
                rs += __expf(acc[e] * (1.0f / 64.0f));
        }
        if (t + 1 < NKT) {
            const int nxt = (t + 1) & 1;
            #pragma unroll
            for (int ii = 0; ii < 4; ++ii) {
                int idx = tid + ii * 256;
                int r = idx >> 4, c = (idx & 15) * 4;
                *reinterpret_cast<bf16x4*>(&Ks[nxt][r][c]) = cvt4(pK[ii]);
            }
            __syncthreads();
        }
    }
    rs += __shfl_xor(rs, 16, 64);
    rs += __shfl_xor(rs, 32, 64);
    const float inv = 1.0f / rs;

    // ====== phase 2: scores -> P(LDS); attn stored ONE TILE LATE (drain overlap) ======
    f32x4 oacc[4];
    #pragma unroll
    for (int n = 0; n < 4; ++n) oacc[n] = {0.f, 0.f, 0.f, 0.f};

    f32x4 pV[4];
    const int vk0 = (tid & 15) * 4;   // V: 4 rows x float4 -> transposed b64 writes
    const int vc  = (tid >> 4) * 4;

    #pragma unroll
    for (int ii = 0; ii < 4; ++ii) {
        int idx = tid + ii * 256;
        int r = idx >> 4, c = (idx & 15) * 4;
        pK[ii] = *reinterpret_cast<const f32x4*>(kg + r * D + c);
        pV[ii] = *reinterpret_cast<const f32x4*>(vg + (vk0 + ii) * D + vc);
    }
    #pragma unroll
    for (int ii = 0; ii < 4; ++ii) {
        int idx = tid + ii * 256;
        int r = idx >> 4, c = (idx & 15) * 4;
        *reinterpret_cast<bf16x4*>(&Ks[0][r][c]) = cvt4(pK[ii]);
    }
    #pragma unroll
    for (int j = 0; j < 4; ++j) {
        f32x4 col = { pV[0][j], pV[1][j], pV[2][j], pV[3][j] };
        *reinterpret_cast<bf16x4*>(&Vt[0][vc + j][vk0]) = cvt4(col);
    }
    __syncthreads();

    for (int t = 0; t < NKT; ++t) {
        const int cur = t & 1;
        // ---- deferred attn store for tile t-1 (QPs still holds its P; own-wave
        // rows only). Issued right AFTER the barrier -> a full tile of compute
        // hides the store completion instead of the barrier draining it. ----
        if (t > 0) {
            #pragma unroll
            for (int h = 0; h < 2; ++h) {
                const int row = wid * 16 + h * 8 + sr;
                #pragma unroll
                for (int half = 0; half < 2; ++half) {
                    bf16x4 pb = *reinterpret_cast<const bf16x4*>(&QPs[row][half * 32 + sc]);
                    f32x4 pf = __builtin_convertvector(pb, f32x4);
                    __builtin_nontemporal_store(pf, reinterpret_cast<f32x4*>(
                        attng + (size_t)row * S + (t - 1) * KT + half * 32 + sc));
                }
            }
        }
        if (t + 1 < NKT) {
            const float* ktg = kg + (size_t)(t + 1) * KT * D;
            const float* vtg = vg + (size_t)(t + 1) * KT * D;
            #pragma unroll
            for (int ii = 0; ii < 4; ++ii) {
                int idx = tid + ii * 256;
                int r = idx >> 4, c = (idx & 15) * 4;
                pK[ii] = *reinterpret_cast<const f32x4*>(ktg + r * D + c);
                pV[ii] = *reinterpret_cast<const f32x4*>(vtg + (vk0 + ii) * D + vc);
            }
        }
        // QK^T (swapped); new P overwrites QPs own-wave rows (same-wave LDS order
        // guarantees the deferred-store reads above complete first)
        #pragma unroll
        for (int cf = 0; cf < 4; ++cf) {
            bf16x8 aK0 = *(const bf16x8*)&Ks[cur][cf * 16 + r16][g * 8];
            bf16x8 aK1 = *(const bf16x8*)&Ks[cur][cf * 16 + r16][32 + g * 8];
            f32x4 acc = {0.f, 0.f, 0.f, 0.f};
            acc = __builtin_amdgcn_mfma_f32_16x16x32_bf16(aK0, bQ0, acc, 0, 0, 0);
            acc = __builtin_amdgcn_mfma_f32_16x16x32_bf16(aK1, bQ1, acc, 0, 0, 0);
            f32x4 pst;
            #pragma unroll
            for (int e = 0; e < 4; ++e)
                pst[e] = __expf(acc[e] * (1.0f / 64.0f)) * inv;
            *reinterpret_cast<bf16x4*>(&QPs[wid * 16 + r16][cf * 16 + g * 4]) = cvt4(pst);
        }
        // PV: A = P (own-wave rows just written; same-wave DS ordering)
        bf16x8 aP0 = *(const bf16x8*)&QPs[wid * 16 + r16][g * 8];
        bf16x8 aP1 = *(const bf16x8*)&QPs[wid * 16 + r16][32 + g * 8];
        #pragma unroll
        for (int n = 0; n < 4; ++n) {
            bf16x8 bv0 = *(const bf16x8*)&Vt[cur][n * 16 + r16][g * 8];
            bf16x8 bv1 = *(const bf16x8*)&Vt[cur][n * 16 + r16][32 + g * 8];
            oacc[n] = __builtin_amdgcn_mfma_f32_16x16x32_bf16(aP0, bv0, oacc[n], 0, 0, 0);
            oacc[n] = __builtin_amdgcn_mfma_f32_16x16x32_bf16(aP1, bv1, oacc[n], 0, 0, 0);
        }
        if (t + 1 < NKT) {
            const int nxt = (t + 1) & 1;
            #pragma unroll
            for (int ii = 0; ii < 4; ++ii) {
                int idx = tid + ii * 256;
                int r = idx >> 4, c = (idx & 15) * 4;
                *reinterpret_cast<bf16x4*>(&Ks[nxt][r][c]) = cvt4(pK[ii]);
            }
            #pragma unroll
            for (int j = 0; j < 4; ++j) {
                f32x4 col = { pV[0][j], pV[1][j], pV[2][j], pV[3][j] };
                *reinterpret_cast<bf16x4*>(&Vt[nxt][vc + j][vk0]) = cvt4(col);
            }
            __syncthreads();
        }
    }

    // ---- final tile's deferred attn store ----
    #pragma unroll
    for (int h = 0; h < 2; ++h) {
        const int row = wid * 16 + h * 8 + sr;
        #pragma unroll
        for (int half = 0; half < 2; ++half) {
            bf16x4 pb = *reinterpret_cast<const bf16x4*>(&QPs[row][half * 32 + sc]);
            f32x4 pf = __builtin_convertvector(pb, f32x4);
            __builtin_nontemporal_store(pf, reinterpret_cast<f32x4*>(
                attng + (size_t)row * S + (NKT - 1) * KT + half * 32 + sc));
        }
    }

    // ---- epilogue: out tile via LDS bounce (Ks dead) -> full-line stores ----
    __syncthreads();   // all waves done with Ks
    float* KsF = reinterpret_cast<float*>(&Ks[0][0][0]);   // 64 x 72 f32
    #pragma unroll
    for (int n = 0; n < 4; ++n) {
        #pragma unroll
        for (int e = 0; e < 4; ++e) {
            KsF[(wid * 16 + g * 4 + e) * 72 + n * 16 + r16] = oacc[n][e];
        }
    }
    __syncthreads();
    #pragma unroll
    for (int h = 0; h < 2; ++h) {
        const int row = wid * 16 + h * 8 + sr;
        #pragma unroll
        for (int half = 0; half < 2; ++half) {
            f32x4 o = *reinterpret_cast<const f32x4*>(&KsF[row * 72 + half * 32 + sc]);
            __builtin_nontemporal_store(o, reinterpret_cast<f32x4*>(
                outg + (size_t)row * D + half * 32 + sc));
        }
    }
}

} // namespace

extern "C" void kernel_launch(void* const* d_in, const int* in_sizes, int n_in,
                              void* d_out, int out_size, void* d_ws, size_t ws_size,
                              hipStream_t stream) {
    const float* q = (const float*)d_in[0];
    const float* k = (const float*)d_in[1];
    const float* v = (const float*)d_in[2];
    float* out  = (float*)d_out;
    float* attn = out + (size_t)BH * S * D;   // outputs concatenated: (out, attn)

    dim3 grid(S / QT, BH);
    sdpa_kernel<<<grid, 256, 0, stream>>>(q, k, v, out, attn);
}

// Round 11
// 125.069 us; speedup vs baseline: 1.0461x; 1.0351x over previous
//
#include <hip/hip_runtime.h>
#include <hip/hip_bf16.h>

namespace {

constexpr int S = 2048;
constexpr int D = 64;
constexpr int BH = 24;        // 2 batches * 12 heads
constexpr int QT = 64;        // q rows per block
constexpr int KT = 64;        // keys per tile
constexpr int NKT = S / KT;   // 32

typedef __attribute__((ext_vector_type(8))) __bf16 bf16x8;
typedef __attribute__((ext_vector_type(4))) __bf16 bf16x4;
typedef __attribute__((ext_vector_type(4))) float  f32x4;

// f32x4 -> bf16x4 via native v_cvt_pk_bf16_f32 (RNE)
__device__ inline bf16x4 cvt4(f32x4 f) {
    return __builtin_convertvector(f, bf16x4);
}

// LDS addressing: stride 64 shorts (128B rows, no pad) + XOR swizzle.
// col in shorts; XOR flips 16B-slot index by (row&7) -> frag reads and P
// writes spread across banks (~2-way max). Every access is an 8B or 16B
// unit, and the XOR only touches bits 3..5 of the short index, so units
// never split. MUST be applied identically at every access site.
__device__ inline int swz(int row, int col) {
    return row * 64 + (col ^ ((row & 7) << 3));
}

__global__ __launch_bounds__(256, 4)
void sdpa_kernel(const float* __restrict__ q,
                 const float* __restrict__ k,
                 const float* __restrict__ v,
                 float* __restrict__ out,
                 float* __restrict__ attn) {
    // 40KB total -> exactly 4 blocks/CU (16 waves): barrier stalls of one
    // block overlap with 3 others (vs 2 at R8's 46KB/3-block config).
    __shared__ unsigned short Ks[2][KT * 64];
    __shared__ unsigned short Vt[2][D * 64];    // [d][key]
    __shared__ unsigned short QPs[QT * 64];     // Q staging, then P (rows wave-private)

    const int tid  = threadIdx.x;
    const int wid  = tid >> 6;       // wave 0..3 owns q rows [wid*16, wid*16+16)
    const int lane = tid & 63;
    const int g    = lane >> 4;      // 16-lane group
    const int r16  = lane & 15;      // q row within wave strip (swapped layout)
    const int sr   = lane >> 3;      // store mapping: 8 rows x 8 lanes
    const int sc   = (lane & 7) * 4; // 4 contiguous elems; 8 lanes = 128B/row
    const int bh   = blockIdx.y;
    const int q0   = blockIdx.x * QT;

    const float* qg = q + ((size_t)bh * S + q0) * D;
    const float* kg = k + (size_t)bh * S * D;
    const float* vg = v + (size_t)bh * S * D;
    float* attng = attn + ((size_t)bh * S + q0) * S;
    float* outg  = out  + ((size_t)bh * S + q0) * D;

    // ---- stage Q tile (QT x D) fp32 -> bf16 LDS ----
    #pragma unroll
    for (int ii = 0; ii < 4; ++ii) {
        int idx = tid + ii * 256;
        int r = idx >> 4, c = (idx & 15) * 4;
        f32x4 f = *reinterpret_cast<const f32x4*>(qg + r * D + c);
        *reinterpret_cast<bf16x4*>(&QPs[swz(r, c)]) = cvt4(f);
    }
    __syncthreads();
    // B-frag (swapped): lane holds Q[q = r16][d = g*8 + j]
    const bf16x8 bQ0 = *(const bf16x8*)&QPs[swz(wid * 16 + r16, g * 8)];
    const bf16x8 bQ1 = *(const bf16x8*)&QPs[swz(wid * 16 + r16, 32 + g * 8)];

    // ================= phase 1: row sums of exp(scores/64) =================
    float rs = 0.0f;
    f32x4 pK[4];

    #pragma unroll
    for (int ii = 0; ii < 4; ++ii) {
        int idx = tid + ii * 256;
        int r = idx >> 4, c = (idx & 15) * 4;
        pK[ii] = *reinterpret_cast<const f32x4*>(kg + r * D + c);
    }
    #pragma unroll
    for (int ii = 0; ii < 4; ++ii) {
        int idx = tid + ii * 256;
        int r = idx >> 4, c = (idx & 15) * 4;
        *reinterpret_cast<bf16x4*>(&Ks[0][swz(r, c)]) = cvt4(pK[ii]);
    }
    __syncthreads();

    for (int t = 0; t < NKT; ++t) {
        const int cur = t & 1;
        if (t + 1 < NKT) {   // prefetch next tile; latency hides under compute
            const float* ktg = kg + (size_t)(t + 1) * KT * D;
            #pragma unroll
            for (int ii = 0; ii < 4; ++ii) {
                int idx = tid + ii * 256;
                int r = idx >> 4, c = (idx & 15) * 4;
                pK[ii] = *reinterpret_cast<const f32x4*>(ktg + r * D + c);
            }
        }
        #pragma unroll
        for (int cf = 0; cf < 4; ++cf) {
            bf16x8 aK0 = *(const bf16x8*)&Ks[cur][swz(cf * 16 + r16, g * 8)];
            bf16x8 aK1 = *(const bf16x8*)&Ks[cur][swz(cf * 16 + r16, 32 + g * 8)];
            f32x4 acc = {0.f, 0.f, 0.f, 0.f};
            acc = __builtin_amdgcn_mfma_f32_16x16x32_bf16(aK0, bQ0, acc, 0, 0, 0);
            acc = __builtin_amdgcn_mfma_f32_16x16x32_bf16(aK1, bQ1, acc, 0, 0, 0);
            #pragma unroll
            for (int e = 0; e < 4; ++e)
                rs += __expf(acc[e] * (1.0f / 64.0f));
        }
        if (t + 1 < NKT) {
            const int nxt = (t + 1) & 1;
            #pragma unroll
            for (int ii = 0; ii < 4; ++ii) {
                int idx = tid + ii * 256;
                int r = idx >> 4, c = (idx & 15) * 4;
                *reinterpret_cast<bf16x4*>(&Ks[nxt][swz(r, c)]) = cvt4(pK[ii]);
            }
            __syncthreads();
        }
    }
    rs += __shfl_xor(rs, 16, 64);
    rs += __shfl_xor(rs, 32, 64);
    const float inv = 1.0f / rs;

    // ====== phase 2: recompute scores, attn via LDS (full-line stores), PV ======
    f32x4 oacc[4];
    #pragma unroll
    for (int n = 0; n < 4; ++n) oacc[n] = {0.f, 0.f, 0.f, 0.f};

    f32x4 pV[4];
    const int vk0 = (tid & 15) * 4;   // V: 4 rows x float4 -> transposed b64 writes
    const int vc  = (tid >> 4) * 4;

    #pragma unroll
    for (int ii = 0; ii < 4; ++ii) {
        int idx = tid + ii * 256;
        int r = idx >> 4, c = (idx & 15) * 4;
        pK[ii] = *reinterpret_cast<const f32x4*>(kg + r * D + c);
        pV[ii] = *reinterpret_cast<const f32x4*>(vg + (vk0 + ii) * D + vc);
    }
    #pragma unroll
    for (int ii = 0; ii < 4; ++ii) {
        int idx = tid + ii * 256;
        int r = idx >> 4, c = (idx & 15) * 4;
        *reinterpret_cast<bf16x4*>(&Ks[0][swz(r, c)]) = cvt4(pK[ii]);
    }
    #pragma unroll
    for (int j = 0; j < 4; ++j) {
        f32x4 col = { pV[0][j], pV[1][j], pV[2][j], pV[3][j] };
        *reinterpret_cast<bf16x4*>(&Vt[0][swz(vc + j, vk0)]) = cvt4(col);
    }
    __syncthreads();

    for (int t = 0; t < NKT; ++t) {
        const int cur = t & 1;
        if (t + 1 < NKT) {
            const float* ktg = kg + (size_t)(t + 1) * KT * D;
            const float* vtg = vg + (size_t)(t + 1) * KT * D;
            #pragma unroll
            for (int ii = 0; ii < 4; ++ii) {
                int idx = tid + ii * 256;
                int r = idx >> 4, c = (idx & 15) * 4;
                pK[ii] = *reinterpret_cast<const f32x4*>(ktg + r * D + c);
                pV[ii] = *reinterpret_cast<const f32x4*>(vtg + (vk0 + ii) * D + vc);
            }
        }
        // QK^T (swapped); P (normalized, bf16) -> own-wave LDS rows
        #pragma unroll
        for (int cf = 0; cf < 4; ++cf) {
            bf16x8 aK0 = *(const bf16x8*)&Ks[cur][swz(cf * 16 + r16, g * 8)];
            bf16x8 aK1 = *(const bf16x8*)&Ks[cur][swz(cf * 16 + r16, 32 + g * 8)];
            f32x4 acc = {0.f, 0.f, 0.f, 0.f};
            acc = __builtin_amdgcn_mfma_f32_16x16x32_bf16(aK0, bQ0, acc, 0, 0, 0);
            acc = __builtin_amdgcn_mfma_f32_16x16x32_bf16(aK1, bQ1, acc, 0, 0, 0);
            f32x4 pst;
            #pragma unroll
            for (int e = 0; e < 4; ++e)
                pst[e] = __expf(acc[e] * (1.0f / 64.0f)) * inv;
            *reinterpret_cast<bf16x4*>(&QPs[swz(wid * 16 + r16, cf * 16 + g * 4)]) = cvt4(pst);
        }
        // PV: A = P (own-wave rows just written; same-wave DS ordering)
        bf16x8 aP0 = *(const bf16x8*)&QPs[swz(wid * 16 + r16, g * 8)];
        bf16x8 aP1 = *(const bf16x8*)&QPs[swz(wid * 16 + r16, 32 + g * 8)];
        #pragma unroll
        for (int n = 0; n < 4; ++n) {
            bf16x8 bv0 = *(const bf16x8*)&Vt[cur][swz(n * 16 + r16, g * 8)];
            bf16x8 bv1 = *(const bf16x8*)&Vt[cur][swz(n * 16 + r16, 32 + g * 8)];
            oacc[n] = __builtin_amdgcn_mfma_f32_16x16x32_bf16(aP0, bv0, oacc[n], 0, 0, 0);
            oacc[n] = __builtin_amdgcn_mfma_f32_16x16x32_bf16(aP1, bv1, oacc[n], 0, 0, 0);
        }
        // attn store from QPs (bf16->f32): 8 rows x (8 lanes x 16B) = full 128B lines
        #pragma unroll
        for (int h = 0; h < 2; ++h) {
            const int row = wid * 16 + h * 8 + sr;
            #pragma unroll
            for (int half = 0; half < 2; ++half) {
                bf16x4 pb = *reinterpret_cast<const bf16x4*>(&QPs[swz(row, half * 32 + sc)]);
                f32x4 pf = __builtin_convertvector(pb, f32x4);
                __builtin_nontemporal_store(pf, reinterpret_cast<f32x4*>(
                    attng + (size_t)row * S + t * KT + half * 32 + sc));
            }
        }
        if (t + 1 < NKT) {
            const int nxt = (t + 1) & 1;
            #pragma unroll
            for (int ii = 0; ii < 4; ++ii) {
                int idx = tid + ii * 256;
                int r = idx >> 4, c = (idx & 15) * 4;
                *reinterpret_cast<bf16x4*>(&Ks[nxt][swz(r, c)]) = cvt4(pK[ii]);
            }
            #pragma unroll
            for (int j = 0; j < 4; ++j) {
                f32x4 col = { pV[0][j], pV[1][j], pV[2][j], pV[3][j] };
                *reinterpret_cast<bf16x4*>(&Vt[nxt][swz(vc + j, vk0)]) = cvt4(col);
            }
            __syncthreads();
        }
    }

    // ---- epilogue: out tile via LDS bounce (Ks dead; 64x64 f32 = 16KB fits Ks) ----
    __syncthreads();   // all waves done with Ks
    float* KsF = reinterpret_cast<float*>(&Ks[0][0]);   // [64][64] f32, linear
    #pragma unroll
    for (int n = 0; n < 4; ++n) {
        #pragma unroll
        for (int e = 0; e < 4; ++e) {
            KsF[(wid * 16 + g * 4 + e) * 64 + n * 16 + r16] = oacc[n][e];
        }
    }
    __syncthreads();
    #pragma unroll
    for (int h = 0; h < 2; ++h) {
        const int row = wid * 16 + h * 8 + sr;
        #pragma unroll
        for (int half = 0; half < 2; ++half) {
            f32x4 o = *reinterpret_cast<const f32x4*>(&KsF[row * 64 + half * 32 + sc]);
            __builtin_nontemporal_store(o, reinterpret_cast<f32x4*>(
                outg + (size_t)row * D + half * 32 + sc));
        }
    }
}

} // namespace

extern "C" void kernel_launch(void* const* d_in, const int* in_sizes, int n_in,
                              void* d_out, int out_size, void* d_ws, size_t ws_size,
                              hipStream_t stream) {
    const float* q = (const float*)d_in[0];
    const float* k = (const float*)d_in[1];
    const float* v = (const float*)d_in[2];
    float* out  = (float*)d_out;
    float* attn = out + (size_t)BH * S * D;   // outputs concatenated: (out, attn)

    dim3 grid(S / QT, BH);
    sdpa_kernel<<<grid, 256, 0, stream>>>(q, k, v, out, attn);
}